// Round 5
// baseline (602.194 us; speedup 1.0000x reference)
//
#include <hip/hip_runtime.h>
#include <math.h>

// B=16, H=64, W=64, C=256; M=65536 pixels. Inputs fp32 (runtime-detected),
// canonicalized to bf16. Compute: bf16 MFMA 16x16x32, fp32 accum.
// R12: attribution round. GEMM reverted to R8's proven 256^2/8-wave/4-phase
// schedule (94us MODE0, FETCH 60.3/WRITE 65.5 clean). R10/R11's lean
// B-in-VGPR variant is retired: 2x replicated at 131us with +69MB/dispatch
// mystery traffic (likely L2-pressure-induced partial-line write-allocate
// on the u16 C-stores). attn keeps R9's sliding 3-col register window
// (2.5x traffic cut, 3x passed, never yet measured on a healthy node).

typedef unsigned short u16;
typedef __bf16 bf16x8 __attribute__((ext_vector_type(8)));
typedef float floatx4 __attribute__((ext_vector_type(4)));

__device__ int g_flag;  // 0 = bf16 inputs, 1 = fp32 inputs
__device__ __align__(16) u16 g_h[16777216];     // canonical bf16 h  [65536,256]
__device__ __align__(16) u16 g_perc[50331648];  // perceived/qkv     [65536,768]
__device__ __align__(16) u16 g_hid[33554432];   // hid               [65536,512]
__device__ __align__(16) u16 g_hnew[16777216];  // h_new             [65536,256]
__device__ __align__(16) u16 g_wperc[6912];
__device__ __align__(16) u16 g_bperc[768];
__device__ __align__(16) u16 g_wup1[393216];
__device__ __align__(16) u16 g_bup1[512];
__device__ __align__(16) u16 g_wup2[131072];
__device__ __align__(16) u16 g_bup2[256];
__device__ __align__(16) u16 g_wqkv[196608];
__device__ __align__(16) u16 g_bqkv[768];

__device__ __forceinline__ float b2f(u16 x) {
  unsigned int u = ((unsigned int)x) << 16;
  float f;
  __builtin_memcpy(&f, &u, 4);
  return f;
}
__device__ __forceinline__ u16 f2b(float f) {
  unsigned int u;
  __builtin_memcpy(&u, &f, 4);
  u += 0x7FFFu + ((u >> 16) & 1u);  // round-to-nearest-even
  return (u16)(u >> 16);
}
// async global->LDS, 16B per lane; LDS dest = wave-uniform base + lane*16.
__device__ __forceinline__ void gload16(const u16* g, u16* l) {
  __builtin_amdgcn_global_load_lds(
      (const __attribute__((address_space(1))) unsigned int*)g,
      (__attribute__((address_space(3))) unsigned int*)l, 16, 0, 0);
}
__device__ __forceinline__ void up8(const uint4& v, float* f) {
  f[0] = b2f((u16)(v.x & 0xFFFF)); f[1] = b2f((u16)(v.x >> 16));
  f[2] = b2f((u16)(v.y & 0xFFFF)); f[3] = b2f((u16)(v.y >> 16));
  f[4] = b2f((u16)(v.z & 0xFFFF)); f[5] = b2f((u16)(v.z >> 16));
  f[6] = b2f((u16)(v.w & 0xFFFF)); f[7] = b2f((u16)(v.w >> 16));
}
__device__ __forceinline__ void ld8(const u16* p, float* f) {
  uint4 v = *(const uint4*)p;
  up8(v, f);
}

// --------------------------------------------------------------------------
// dtype probe: even u16 halves of fp32 data hit exp==0xFF w.p. 1/256;
// bf16 N(0,1) data never does.
// --------------------------------------------------------------------------
__global__ __launch_bounds__(256) void probe_kernel(const u16* __restrict__ h) {
  __shared__ int hit;
  if (threadIdx.x == 0) hit = 0;
  __syncthreads();
  int local = 0;
  for (int i = threadIdx.x; i < 8192; i += 256) {
    u16 v = h[2 * i];
    if ((v & 0x7F80) == 0x7F80) local = 1;
  }
  if (local) atomicOr(&hit, 1);
  __syncthreads();
  if (threadIdx.x == 0) g_flag = hit;
}

// canonicalize all 8 weight/bias tensors in one launch
__global__ __launch_bounds__(256) void conv_w_kernel(
    const void* i1, const void* i2, const void* i3, const void* i4,
    const void* i5, const void* i6, const void* i7, const void* i8) {
  const void* srcs[8] = {i1, i2, i3, i4, i5, i6, i7, i8};
  u16* dsts[8] = {g_wperc, g_bperc, g_wup1, g_bup1,
                  g_wup2,  g_bup2,  g_wqkv, g_bqkv};
  const int szs[8] = {6912, 768, 393216, 512, 131072, 256, 196608, 768};
  const int fp32 = g_flag;
  const int stride = gridDim.x * 256;
  for (int gw = blockIdx.x * 256 + threadIdx.x; gw < 730112; gw += stride) {
    int seg = 0, off = gw;
    while (off >= szs[seg]) { off -= szs[seg]; ++seg; }
    dsts[seg][off] = fp32 ? f2b(((const float*)srcs[seg])[off])
                          : ((const u16*)srcs[seg])[off];
  }
}

// --------------------------------------------------------------------------
// grouped 3x3 perception conv fused with h->bf16 canonicalization.
// grid 2048: blockIdx = (b*64+y)*2 + channel-half. Wave = 16-px x-strip,
// lane = 2-channel group (w[2][27] ~ 95 VGPR, no spill). FULL unroll so the
// sliding-window slot indices are compile-time constants (hv stays in VGPRs).
// Reads raw h (fp32/bf16 per g_flag); writes g_h (bf16) + g_perc [pix][768].
// --------------------------------------------------------------------------
__global__ __launch_bounds__(256) void perc_kernel(const void* __restrict__ hin) {
  __shared__ __align__(16) u16 sw[3456];
  __shared__ __align__(16) u16 sb[384];
  const int bid = blockIdx.x >> 1;  // b*64 + y
  const int chalf = blockIdx.x & 1;
  const int b = bid >> 6, y = bid & 63;
  const int xi = threadIdx.x >> 6;  // wave id: x-strip
  const int cl = threadIdx.x & 63;  // 2-channel group within half
  const int c0 = chalf * 128 + cl * 2;
  for (int i = threadIdx.x; i < 3456; i += 256) sw[i] = g_wperc[chalf * 3456 + i];
  for (int i = threadIdx.x; i < 384; i += 256) sb[i] = g_bperc[chalf * 384 + i];
  const int fp32 = g_flag;
  __syncthreads();
  float w[2][27], bias[2][3];
#pragma unroll
  for (int ch = 0; ch < 2; ++ch) {
    const int lc = cl * 2 + ch;  // local channel within half
#pragma unroll
    for (int t = 0; t < 3; ++t) {
      bias[ch][t] = b2f(sb[3 * lc + t]);
#pragma unroll
      for (int j = 0; j < 9; ++j)
        w[ch][t * 9 + j] = b2f(sw[(3 * lc + t) * 9 + j]);
    }
  }
  float hv[3][3][2];  // [row][colslot][ch]
  auto loadcol = [&](int xx, int cc) {
#pragma unroll
    for (int r = 0; r < 3; ++r) {
      const int yy = y - 1 + r;
      const bool ok = ((unsigned)yy < 64u) && ((unsigned)xx < 64u);
      if (ok) {
        const size_t idx = (((size_t)(b * 64 + yy) * 64) + xx) * 256 + c0;
        if (fp32) {
          const float2 v = *(const float2*)((const float*)hin + idx);
          hv[r][cc][0] = v.x;
          hv[r][cc][1] = v.y;
        } else {
          const unsigned v = *(const unsigned*)((const u16*)hin + idx);
          hv[r][cc][0] = b2f((u16)(v & 0xFFFF));
          hv[r][cc][1] = b2f((u16)(v >> 16));
        }
      } else {
        hv[r][cc][0] = 0.0f;
        hv[r][cc][1] = 0.0f;
      }
    }
  };
  const int x0 = xi * 16;
  loadcol(x0 - 1, 0);
  loadcol(x0, 1);
#pragma unroll
  for (int k = 0; k < 16; ++k) {
    const int x = x0 + k;
    loadcol(x + 1, (k + 2) % 3);
    const int cL = k % 3, cM = (k + 1) % 3, cR = (k + 2) % 3;
    const size_t pix = (size_t)(b * 64 + y) * 64 + x;
    // canonical bf16 h (center; exact round-trip for bf16 inputs)
    *(unsigned*)&g_h[pix * 256 + c0] =
        (unsigned)f2b(hv[1][cM][0]) | ((unsigned)f2b(hv[1][cM][1]) << 16);
    u16* op = &g_perc[pix * 768 + 3 * c0];  // lane stride 6 u16 = 12 B
    unsigned pk[3];
#pragma unroll
    for (int ch = 0; ch < 2; ++ch) {
#pragma unroll
      for (int t = 0; t < 3; ++t) {
        const float* wt = &w[ch][t * 9];
        float a = bias[ch][t];
        a += hv[0][cL][ch] * wt[0] + hv[0][cM][ch] * wt[1] + hv[0][cR][ch] * wt[2];
        a += hv[1][cL][ch] * wt[3] + hv[1][cM][ch] * wt[4] + hv[1][cR][ch] * wt[5];
        a += hv[2][cL][ch] * wt[6] + hv[2][cM][ch] * wt[7] + hv[2][cR][ch] * wt[8];
        const int o = 3 * ch + t;
        const unsigned bb = f2b(a);
        if (o & 1) pk[o >> 1] |= bb << 16; else pk[o >> 1] = bb;
      }
    }
    *(unsigned*)(op) = pk[0];      // 12 B per lane as 3 dword stores
    *(unsigned*)(op + 2) = pk[1];  // (4-aligned; 8-alignment not guaranteed)
    *(unsigned*)(op + 4) = pk[2];
  }
}

// --------------------------------------------------------------------------
// MFMA bf16 GEMM: C[M,N] = epi(A[M,K] * W[N,K]^T + bias[N])  — R8 structure.
// BM=BN=256, BK=64, 512 threads = 8 waves (2M x 4N), per-wave 128x64 output
// via interleaved fragments: m=(f*2+wmi)*16, n=(g*4+wni)*16. LDS = 2 K-tile
// buffers x (A,B) x 2 halves x 16KB = 128KB. 4 phases per K-tile u; phase r
// computes quadrant (ah,bh) in {(0,0),(0,1),(1,1),(1,0)} (16 MFMA) and
// stages one half-tile: r0:Ah1(u+1) r1:Bh0(u+1) r2:Ah0(u+2) r3:Bh1(u+2).
// One s_waitcnt vmcnt(6) per K-tile (3 half-tiles in flight), vmcnt(0) only
// at the last tile. Stage swizzle: 16B slot s holds global chunk
// ((s>>3),(s&7)^((s>>3)&7)) -> ds_read_b128 measured conflict-free.
// MODE 0: perceived@wup1 +GELU -> hid.  MODE 1: hid@wup2 +h -> hnew.
// MODE 2: hnew@wqkv -> qkv (g_perc reuse).
// --------------------------------------------------------------------------
template <int MODE, int NB>
__global__ __launch_bounds__(512) void gemm_bt(int K) {
  const u16 *A, *Bw, *bias, *resid;
  u16* C;
  if (MODE == 0) { A = g_perc; Bw = g_wup1; bias = g_bup1; resid = nullptr; C = g_hid; }
  if (MODE == 1) { A = g_hid;  Bw = g_wup2; bias = g_bup2; resid = g_h;     C = g_hnew; }
  if (MODE == 2) { A = g_hnew; Bw = g_wqkv; bias = g_bqkv; resid = nullptr; C = g_perc; }
  const int N = NB * 256;
  const int NT = K >> 6;  // K-tiles of 64 (12 / 8 / 4)

  __shared__ __align__(16) u16 lds[2][2][2][8192];  // [buf][A|B][half][128*64]
  const int tid = threadIdx.x;
  const int w = tid >> 6, lane = tid & 63;
  const int ln = lane & 15, quad = lane >> 4, lnx = ln & 7;
  const int wmi = w >> 2, wni = w & 3;  // 2M x 4N wave grid

  const int mb_per_xcd = (gridDim.x / NB) >> 3;
  const int m_blk = (blockIdx.x & 7) * mb_per_xcd + (blockIdx.x >> 3) / NB;
  const int n_blk = (blockIdx.x >> 3) % NB;
  const int m0 = m_blk * 256, n0 = n_blk * 256;

  auto stageA = [&](int t, int half) {
    u16* dst = &lds[t & 1][0][half][0];
#pragma unroll
    for (int ld = 0; ld < 2; ++ld) {
      const int s = ld * 512 + tid;
      const int srow = s >> 3, sch = (s & 7) ^ (srow & 7);
      gload16(&A[(size_t)(m0 + half * 128 + srow) * K + t * 64 + sch * 8],
              dst + s * 8);
    }
  };
  auto stageB = [&](int t, int half) {
    u16* dst = &lds[t & 1][1][half][0];
#pragma unroll
    for (int ld = 0; ld < 2; ++ld) {
      const int s = ld * 512 + tid;
      const int srow = s >> 3, sch = (s & 7) ^ (srow & 7);
      gload16(&Bw[(size_t)(n0 + half * 128 + srow) * K + t * 64 + sch * 8],
              dst + s * 8);
    }
  };

  floatx4 acc[8][4] = {};
  bf16x8 af[4][2], bfr[2][2];

  // prologue = steady-state stages of phases -6..-1 (NT >= 4 always)
  stageA(0, 0); stageB(0, 1); stageA(0, 1); stageB(0, 0);
  stageA(1, 0); stageB(1, 1);

  for (int u = 0; u < NT; ++u) {
    const u16* Abuf = &lds[u & 1][0][0][0];
    const u16* Bbuf = &lds[u & 1][1][0][0];
#pragma unroll
    for (int r = 0; r < 4; ++r) {
      if (r == 0 && u + 1 < NT) stageA(u + 1, 1);
      if (r == 1 && u + 1 < NT) stageB(u + 1, 0);
      if (r == 2 && u + 2 < NT) stageA(u + 2, 0);
      if (r == 3 && u + 2 < NT) stageB(u + 2, 1);
      if (r == 0) {
        if (u + 1 < NT) asm volatile("s_waitcnt vmcnt(6)" ::: "memory");
        else            asm volatile("s_waitcnt vmcnt(0)" ::: "memory");
      }
      asm volatile("s_barrier" ::: "memory");
      const int ah = (r >= 2) ? 1 : 0;
      const int bh = (r == 1 || r == 2) ? 1 : 0;
      if (r == 0 || r == 2) {  // fresh A-half (reused by the next phase)
#pragma unroll
        for (int f2 = 0; f2 < 4; ++f2) {
          const int row = (f2 * 2 + wmi) * 16 + ln;
#pragma unroll
          for (int ks = 0; ks < 2; ++ks) {
            const int ch = (ks * 4 + quad) ^ lnx;
            af[f2][ks] = *(const bf16x8*)(Abuf + ah * 8192 + (row * 8 + ch) * 8);
          }
        }
      }
      if (r != 2) {  // fresh B-half (r2 reuses r1's bh=1)
#pragma unroll
        for (int g2 = 0; g2 < 2; ++g2) {
          const int row = (g2 * 4 + wni) * 16 + ln;
#pragma unroll
          for (int ks = 0; ks < 2; ++ks) {
            const int ch = (ks * 4 + quad) ^ lnx;
            bfr[g2][ks] = *(const bf16x8*)(Bbuf + bh * 8192 + (row * 8 + ch) * 8);
          }
        }
      }
      __builtin_amdgcn_s_setprio(1);
#pragma unroll
      for (int f2 = 0; f2 < 4; ++f2)
#pragma unroll
        for (int g2 = 0; g2 < 2; ++g2)
#pragma unroll
          for (int ks = 0; ks < 2; ++ks)
            acc[ah * 4 + f2][bh * 2 + g2] =
                __builtin_amdgcn_mfma_f32_16x16x32_bf16(
                    af[f2][ks], bfr[g2][ks], acc[ah * 4 + f2][bh * 2 + g2],
                    0, 0, 0);
      __builtin_amdgcn_s_setprio(0);
      asm volatile("s_barrier" ::: "memory");
    }
  }

#pragma unroll
  for (int f = 0; f < 8; ++f) {
    const int mB = m0 + (f * 2 + wmi) * 16 + quad * 4;
#pragma unroll
    for (int g = 0; g < 4; ++g) {
      const int n = n0 + (g * 4 + wni) * 16 + ln;
      const float bv = b2f(bias[n]);
#pragma unroll
      for (int rr = 0; rr < 4; ++rr) {
        float v = acc[f][g][rr] + bv;
        if (MODE == 0) v = 0.5f * v * (1.0f + erff(v * 0.70710678118654752f));
        if (MODE == 1) v += b2f(resid[(size_t)(mB + rr) * N + n]);
        C[(size_t)(mB + rr) * N + n] = f2b(v);
      }
    }
  }
}

// --------------------------------------------------------------------------
// 3x3 windowed local attention (zero-padded borders), sliding-window form.
// Each 32-lane half-wave owns an 8-px x-run; lane = 8 channels. K/V halo
// (3 rows x 3 col-slots) lives in packed uint4 regs; 1-px-ahead prefetch
// into tmp regs hides load latency under the previous pixel's VALU work.
// OOB cols/rows are zero-filled: zero score enters softmax (== reference's
// zero-padded K) and zero V contributes nothing. out = hnew + attn.
// --------------------------------------------------------------------------
__global__ __launch_bounds__(256) void attn_kernel(void* __restrict__ outv) {
  const int wv = threadIdx.x >> 6, lane = threadIdx.x & 63;
  const int half = lane >> 5, cl = lane & 31;
  const int c0 = cl * 8;
  const int run = blockIdx.x * 8 + wv * 2 + half;  // 8192 runs of 8 px
  const int row = run >> 3;                        // absolute row b*64+y
  const int y = row & 63;
  const int x0 = (run & 7) * 8;
  const int fp32 = g_flag;

  uint4 Kw[3][3], Vw[3][3], tK[3], tV[3];
  auto fetch = [&](int xx, uint4 (&K3)[3], uint4 (&V3)[3]) {
#pragma unroll
    for (int r = 0; r < 3; ++r) {
      const int yy = y - 1 + r;
      if (((unsigned)yy < 64u) && ((unsigned)xx < 64u)) {
        const size_t np = (size_t)(row - 1 + r) * 64 + xx;
        K3[r] = *(const uint4*)(g_perc + np * 768 + 256 + c0);
        V3[r] = *(const uint4*)(g_perc + np * 768 + 512 + c0);
      } else {
        K3[r] = make_uint4(0, 0, 0, 0);
        V3[r] = make_uint4(0, 0, 0, 0);
      }
    }
  };
  // prologue: cols x0-1 -> slot0, x0 -> slot1, x0+1 -> tmp
  fetch(x0 - 1, tK, tV);
#pragma unroll
  for (int r = 0; r < 3; ++r) { Kw[r][0] = tK[r]; Vw[r][0] = tV[r]; }
  fetch(x0, tK, tV);
#pragma unroll
  for (int r = 0; r < 3; ++r) { Kw[r][1] = tK[r]; Vw[r][1] = tV[r]; }
  fetch(x0 + 1, tK, tV);

#pragma unroll
  for (int k = 0; k < 8; ++k) {
    const int x = x0 + k;
    const int sR = (k + 2) % 3;  // slot receiving col x+1 (from tmp)
#pragma unroll
    for (int r = 0; r < 3; ++r) { Kw[r][sR] = tK[r]; Vw[r][sR] = tV[r]; }
    fetch(x + 2, tK, tV);  // prefetch next px's right col (OOB-safe)

    const size_t pix = (size_t)row * 64 + x;
    float q[8];
    ld8(g_perc + pix * 768 + c0, q);
    float a[8];
    ld8(g_hnew + pix * 256 + c0, a);

    float s[9];
#pragma unroll
    for (int j = 0; j < 9; ++j) {
      float kv[8];
      up8(Kw[j / 3][(k + j % 3) % 3], kv);  // col x-1+(j%3)
      float p = q[0] * kv[0] + q[1] * kv[1] + q[2] * kv[2] + q[3] * kv[3] +
                q[4] * kv[4] + q[5] * kv[5] + q[6] * kv[6] + q[7] * kv[7];
#pragma unroll
      for (int off = 16; off >= 1; off >>= 1) p += __shfl_xor(p, off, 64);
      s[j] = p * 0.0625f;  // 1/sqrt(256)
    }
    float mx = s[0];
#pragma unroll
    for (int j = 1; j < 9; ++j) mx = fmaxf(mx, s[j]);
    float e[9], den = 0.0f;
#pragma unroll
    for (int j = 0; j < 9; ++j) {
      e[j] = expf(s[j] - mx);
      den += e[j];
    }
    const float inv = 1.0f / den;
#pragma unroll
    for (int j = 0; j < 9; ++j) {
      const float wgt = e[j] * inv;
      float vv[8];
      up8(Vw[j / 3][(k + j % 3) % 3], vv);
#pragma unroll
      for (int t = 0; t < 8; ++t) a[t] += wgt * vv[t];
    }
    const size_t o = pix * 256 + c0;
    if (fp32) {
      float4 r0 = {a[0], a[1], a[2], a[3]};
      float4 r1 = {a[4], a[5], a[6], a[7]};
      *(float4*)((float*)outv + o) = r0;
      *(float4*)((float*)outv + o + 4) = r1;
    } else {
      uint4 r;
      r.x = (unsigned)f2b(a[0]) | ((unsigned)f2b(a[1]) << 16);
      r.y = (unsigned)f2b(a[2]) | ((unsigned)f2b(a[3]) << 16);
      r.z = (unsigned)f2b(a[4]) | ((unsigned)f2b(a[5]) << 16);
      r.w = (unsigned)f2b(a[6]) | ((unsigned)f2b(a[7]) << 16);
      *(uint4*)((u16*)outv + o) = r;
    }
  }
}

// --------------------------------------------------------------------------
extern "C" void kernel_launch(void* const* d_in, const int* in_sizes, int n_in,
                              void* d_out, int d_out_size, void* d_ws,
                              size_t ws_size, hipStream_t stream) {
  (void)d_ws; (void)ws_size;
  probe_kernel<<<1, 256, 0, stream>>>((const u16*)d_in[0]);
  conv_w_kernel<<<360, 256, 0, stream>>>(d_in[1], d_in[2], d_in[3], d_in[4],
                                         d_in[5], d_in[6], d_in[7], d_in[8]);
  // perception + h canonicalization (2048 blocks: (b,y) x channel-half)
  perc_kernel<<<2048, 256, 0, stream>>>(d_in[0]);
  // hid = GELU(perceived @ w_up1^T + b_up1)   [65536 x 512, K=768]
  gemm_bt<0, 2><<<512, 512, 0, stream>>>(768);
  // h_new = h + hid @ w_up2^T + b_up2         [65536 x 256, K=512]
  gemm_bt<1, 1><<<256, 512, 0, stream>>>(512);
  // qkv = h_new @ w_qkv^T + b_qkv             [65536 x 768, K=256]
  gemm_bt<2, 3><<<768, 512, 0, stream>>>(256);
  // out = h_new + local_attn(qkv)  (8192 runs of 8 px, 8 runs/block)
  attn_kernel<<<1024, 256, 0, stream>>>(d_out);
}

// Round 6
// 583.892 us; speedup vs baseline: 1.0313x; 1.0313x over previous
//
#include <hip/hip_runtime.h>
#include <math.h>

// B=16, H=64, W=64, C=256; M=65536 pixels. Inputs fp32 (runtime-detected),
// canonicalized to bf16. Compute: bf16 MFMA 16x16x32, fp32 accum.
// R13: two changes on top of R12 (R8 GEMM + R9 attn, the best-known config):
//  1) GEMM epilogue staged through LDS: acc -> 128 ds_write_b16 (bank-skewed
//     264-u16 stride, 2 chunks of 128 rows) -> 8 contiguous uint4 global
//     stores/thread. Replaces 128 scattered 2B stores (and for MODE1, 128
//     scattered 2B resid reads -> coalesced uint4). Epilogue is the one
//     element shared by all three ~95us GEMM structures; m201's coalesced-
//     epilogue template hits 62% MfmaUtil vs our 22%.
//  2) XCD-chunked block swizzle for perc and attn (T1): adjacent-y blocks
//     share 2/3 halo rows (fp32 h = biggest read stream); chunking puts them
//     on one XCD's L2 instead of round-robin across 8.
// Node-speed note: R9/R12 ran on throttled nodes (identical gemm code+bytes,
// x0.614 uniform). Use gemm MODE0 dispatch as in-run clock anchor.

typedef unsigned short u16;
typedef __bf16 bf16x8 __attribute__((ext_vector_type(8)));
typedef float floatx4 __attribute__((ext_vector_type(4)));

__device__ int g_flag;  // 0 = bf16 inputs, 1 = fp32 inputs
__device__ __align__(16) u16 g_h[16777216];     // canonical bf16 h  [65536,256]
__device__ __align__(16) u16 g_perc[50331648];  // perceived/qkv     [65536,768]
__device__ __align__(16) u16 g_hid[33554432];   // hid               [65536,512]
__device__ __align__(16) u16 g_hnew[16777216];  // h_new             [65536,256]
__device__ __align__(16) u16 g_wperc[6912];
__device__ __align__(16) u16 g_bperc[768];
__device__ __align__(16) u16 g_wup1[393216];
__device__ __align__(16) u16 g_bup1[512];
__device__ __align__(16) u16 g_wup2[131072];
__device__ __align__(16) u16 g_bup2[256];
__device__ __align__(16) u16 g_wqkv[196608];
__device__ __align__(16) u16 g_bqkv[768];

__device__ __forceinline__ float b2f(u16 x) {
  unsigned int u = ((unsigned int)x) << 16;
  float f;
  __builtin_memcpy(&f, &u, 4);
  return f;
}
__device__ __forceinline__ u16 f2b(float f) {
  unsigned int u;
  __builtin_memcpy(&u, &f, 4);
  u += 0x7FFFu + ((u >> 16) & 1u);  // round-to-nearest-even
  return (u16)(u >> 16);
}
// async global->LDS, 16B per lane; LDS dest = wave-uniform base + lane*16.
__device__ __forceinline__ void gload16(const u16* g, u16* l) {
  __builtin_amdgcn_global_load_lds(
      (const __attribute__((address_space(1))) unsigned int*)g,
      (__attribute__((address_space(3))) unsigned int*)l, 16, 0, 0);
}
__device__ __forceinline__ void up8(const uint4& v, float* f) {
  f[0] = b2f((u16)(v.x & 0xFFFF)); f[1] = b2f((u16)(v.x >> 16));
  f[2] = b2f((u16)(v.y & 0xFFFF)); f[3] = b2f((u16)(v.y >> 16));
  f[4] = b2f((u16)(v.z & 0xFFFF)); f[5] = b2f((u16)(v.z >> 16));
  f[6] = b2f((u16)(v.w & 0xFFFF)); f[7] = b2f((u16)(v.w >> 16));
}
__device__ __forceinline__ void ld8(const u16* p, float* f) {
  uint4 v = *(const uint4*)p;
  up8(v, f);
}

// --------------------------------------------------------------------------
// dtype probe: even u16 halves of fp32 data hit exp==0xFF w.p. 1/256;
// bf16 N(0,1) data never does.
// --------------------------------------------------------------------------
__global__ __launch_bounds__(256) void probe_kernel(const u16* __restrict__ h) {
  __shared__ int hit;
  if (threadIdx.x == 0) hit = 0;
  __syncthreads();
  int local = 0;
  for (int i = threadIdx.x; i < 8192; i += 256) {
    u16 v = h[2 * i];
    if ((v & 0x7F80) == 0x7F80) local = 1;
  }
  if (local) atomicOr(&hit, 1);
  __syncthreads();
  if (threadIdx.x == 0) g_flag = hit;
}

// canonicalize all 8 weight/bias tensors in one launch
__global__ __launch_bounds__(256) void conv_w_kernel(
    const void* i1, const void* i2, const void* i3, const void* i4,
    const void* i5, const void* i6, const void* i7, const void* i8) {
  const void* srcs[8] = {i1, i2, i3, i4, i5, i6, i7, i8};
  u16* dsts[8] = {g_wperc, g_bperc, g_wup1, g_bup1,
                  g_wup2,  g_bup2,  g_wqkv, g_bqkv};
  const int szs[8] = {6912, 768, 393216, 512, 131072, 256, 196608, 768};
  const int fp32 = g_flag;
  const int stride = gridDim.x * 256;
  for (int gw = blockIdx.x * 256 + threadIdx.x; gw < 730112; gw += stride) {
    int seg = 0, off = gw;
    while (off >= szs[seg]) { off -= szs[seg]; ++seg; }
    dsts[seg][off] = fp32 ? f2b(((const float*)srcs[seg])[off])
                          : ((const u16*)srcs[seg])[off];
  }
}

// --------------------------------------------------------------------------
// grouped 3x3 perception conv fused with h->bf16 canonicalization.
// 2048 blocks, XCD-chunked: physical block p serves logical lb =
// (p&7)*256 + (p>>3), so 256 consecutive lb (128 consecutive y-rows) share
// one XCD -> halo rows (2/3 of the fp32 h read stream) become L2 hits.
// Wave = 16-px x-strip, lane = 2-channel group. FULL unroll (hv in VGPRs).
// Reads raw h (fp32/bf16 per g_flag); writes g_h (bf16) + g_perc [pix][768].
// --------------------------------------------------------------------------
__global__ __launch_bounds__(256) void perc_kernel(const void* __restrict__ hin) {
  __shared__ __align__(16) u16 sw[3456];
  __shared__ __align__(16) u16 sb[384];
  const int lb = (blockIdx.x & 7) * 256 + (blockIdx.x >> 3);  // XCD chunk
  const int bid = lb >> 1;  // b*64 + y
  const int chalf = lb & 1;
  const int b = bid >> 6, y = bid & 63;
  const int xi = threadIdx.x >> 6;  // wave id: x-strip
  const int cl = threadIdx.x & 63;  // 2-channel group within half
  const int c0 = chalf * 128 + cl * 2;
  for (int i = threadIdx.x; i < 3456; i += 256) sw[i] = g_wperc[chalf * 3456 + i];
  for (int i = threadIdx.x; i < 384; i += 256) sb[i] = g_bperc[chalf * 384 + i];
  const int fp32 = g_flag;
  __syncthreads();
  float w[2][27], bias[2][3];
#pragma unroll
  for (int ch = 0; ch < 2; ++ch) {
    const int lc = cl * 2 + ch;  // local channel within half
#pragma unroll
    for (int t = 0; t < 3; ++t) {
      bias[ch][t] = b2f(sb[3 * lc + t]);
#pragma unroll
      for (int j = 0; j < 9; ++j)
        w[ch][t * 9 + j] = b2f(sw[(3 * lc + t) * 9 + j]);
    }
  }
  float hv[3][3][2];  // [row][colslot][ch]
  auto loadcol = [&](int xx, int cc) {
#pragma unroll
    for (int r = 0; r < 3; ++r) {
      const int yy = y - 1 + r;
      const bool ok = ((unsigned)yy < 64u) && ((unsigned)xx < 64u);
      if (ok) {
        const size_t idx = (((size_t)(b * 64 + yy) * 64) + xx) * 256 + c0;
        if (fp32) {
          const float2 v = *(const float2*)((const float*)hin + idx);
          hv[r][cc][0] = v.x;
          hv[r][cc][1] = v.y;
        } else {
          const unsigned v = *(const unsigned*)((const u16*)hin + idx);
          hv[r][cc][0] = b2f((u16)(v & 0xFFFF));
          hv[r][cc][1] = b2f((u16)(v >> 16));
        }
      } else {
        hv[r][cc][0] = 0.0f;
        hv[r][cc][1] = 0.0f;
      }
    }
  };
  const int x0 = xi * 16;
  loadcol(x0 - 1, 0);
  loadcol(x0, 1);
#pragma unroll
  for (int k = 0; k < 16; ++k) {
    const int x = x0 + k;
    loadcol(x + 1, (k + 2) % 3);
    const int cL = k % 3, cM = (k + 1) % 3, cR = (k + 2) % 3;
    const size_t pix = (size_t)(b * 64 + y) * 64 + x;
    // canonical bf16 h (center; exact round-trip for bf16 inputs)
    *(unsigned*)&g_h[pix * 256 + c0] =
        (unsigned)f2b(hv[1][cM][0]) | ((unsigned)f2b(hv[1][cM][1]) << 16);
    u16* op = &g_perc[pix * 768 + 3 * c0];  // lane stride 6 u16 = 12 B
    unsigned pk[3];
#pragma unroll
    for (int ch = 0; ch < 2; ++ch) {
#pragma unroll
      for (int t = 0; t < 3; ++t) {
        const float* wt = &w[ch][t * 9];
        float a = bias[ch][t];
        a += hv[0][cL][ch] * wt[0] + hv[0][cM][ch] * wt[1] + hv[0][cR][ch] * wt[2];
        a += hv[1][cL][ch] * wt[3] + hv[1][cM][ch] * wt[4] + hv[1][cR][ch] * wt[5];
        a += hv[2][cL][ch] * wt[6] + hv[2][cM][ch] * wt[7] + hv[2][cR][ch] * wt[8];
        const int o = 3 * ch + t;
        const unsigned bb = f2b(a);
        if (o & 1) pk[o >> 1] |= bb << 16; else pk[o >> 1] = bb;
      }
    }
    *(unsigned*)(op) = pk[0];      // 12 B per lane as 3 dword stores
    *(unsigned*)(op + 2) = pk[1];  // (4-aligned; 8-alignment not guaranteed)
    *(unsigned*)(op + 4) = pk[2];
  }
}

// --------------------------------------------------------------------------
// MFMA bf16 GEMM: C[M,N] = epi(A[M,K] * W[N,K]^T + bias[N])  — R8 K-loop.
// BM=BN=256, BK=64, 512 threads = 8 waves (2M x 4N), per-wave 128x64 output
// via interleaved fragments: m=(f*2+wmi)*16, n=(g*4+wni)*16. LDS = 2 K-tile
// buffers x (A,B) x 2 halves x 16KB = 128KB. 4 phases per K-tile; phase r
// computes quadrant (ah,bh) in {(0,0),(0,1),(1,1),(1,0)} (16 MFMA) and
// stages one half-tile. One s_waitcnt vmcnt(6) per K-tile; vmcnt(0) only at
// the last tile. Chunk-XOR stage swizzle -> conflict-free ds_read_b128.
// R13 epilogue: LDS-staged coalesced C store (2 chunks of 128 rows, 264-u16
// row stride: 16B-aligned + bank-skewed). MODE1 resid added in read phase
// as coalesced uint4 (1-ulp double-round vs before; within tolerance).
// MODE 0: perceived@wup1 +GELU -> hid.  MODE 1: hid@wup2 +h -> hnew.
// MODE 2: hnew@wqkv -> qkv (g_perc reuse).
// --------------------------------------------------------------------------
template <int MODE, int NB>
__global__ __launch_bounds__(512) void gemm_bt(int K) {
  const u16 *A, *Bw, *bias, *resid;
  u16* C;
  if (MODE == 0) { A = g_perc; Bw = g_wup1; bias = g_bup1; resid = nullptr; C = g_hid; }
  if (MODE == 1) { A = g_hid;  Bw = g_wup2; bias = g_bup2; resid = g_h;     C = g_hnew; }
  if (MODE == 2) { A = g_hnew; Bw = g_wqkv; bias = g_bqkv; resid = nullptr; C = g_perc; }
  const int N = NB * 256;
  const int NT = K >> 6;  // K-tiles of 64 (12 / 8 / 4)

  __shared__ __align__(16) u16 lds[2][2][2][8192];  // [buf][A|B][half][128*64]
  const int tid = threadIdx.x;
  const int w = tid >> 6, lane = tid & 63;
  const int ln = lane & 15, quad = lane >> 4, lnx = ln & 7;
  const int wmi = w >> 2, wni = w & 3;  // 2M x 4N wave grid

  const int mb_per_xcd = (gridDim.x / NB) >> 3;
  const int m_blk = (blockIdx.x & 7) * mb_per_xcd + (blockIdx.x >> 3) / NB;
  const int n_blk = (blockIdx.x >> 3) % NB;
  const int m0 = m_blk * 256, n0 = n_blk * 256;

  auto stageA = [&](int t, int half) {
    u16* dst = &lds[t & 1][0][half][0];
#pragma unroll
    for (int ld = 0; ld < 2; ++ld) {
      const int s = ld * 512 + tid;
      const int srow = s >> 3, sch = (s & 7) ^ (srow & 7);
      gload16(&A[(size_t)(m0 + half * 128 + srow) * K + t * 64 + sch * 8],
              dst + s * 8);
    }
  };
  auto stageB = [&](int t, int half) {
    u16* dst = &lds[t & 1][1][half][0];
#pragma unroll
    for (int ld = 0; ld < 2; ++ld) {
      const int s = ld * 512 + tid;
      const int srow = s >> 3, sch = (s & 7) ^ (srow & 7);
      gload16(&Bw[(size_t)(n0 + half * 128 + srow) * K + t * 64 + sch * 8],
              dst + s * 8);
    }
  };

  floatx4 acc[8][4] = {};
  bf16x8 af[4][2], bfr[2][2];

  // prologue = steady-state stages of phases -6..-1 (NT >= 4 always)
  stageA(0, 0); stageB(0, 1); stageA(0, 1); stageB(0, 0);
  stageA(1, 0); stageB(1, 1);

  for (int u = 0; u < NT; ++u) {
    const u16* Abuf = &lds[u & 1][0][0][0];
    const u16* Bbuf = &lds[u & 1][1][0][0];
#pragma unroll
    for (int r = 0; r < 4; ++r) {
      if (r == 0 && u + 1 < NT) stageA(u + 1, 1);
      if (r == 1 && u + 1 < NT) stageB(u + 1, 0);
      if (r == 2 && u + 2 < NT) stageA(u + 2, 0);
      if (r == 3 && u + 2 < NT) stageB(u + 2, 1);
      if (r == 0) {
        if (u + 1 < NT) asm volatile("s_waitcnt vmcnt(6)" ::: "memory");
        else            asm volatile("s_waitcnt vmcnt(0)" ::: "memory");
      }
      asm volatile("s_barrier" ::: "memory");
      const int ah = (r >= 2) ? 1 : 0;
      const int bh = (r == 1 || r == 2) ? 1 : 0;
      if (r == 0 || r == 2) {  // fresh A-half (reused by the next phase)
#pragma unroll
        for (int f2 = 0; f2 < 4; ++f2) {
          const int row = (f2 * 2 + wmi) * 16 + ln;
#pragma unroll
          for (int ks = 0; ks < 2; ++ks) {
            const int ch = (ks * 4 + quad) ^ lnx;
            af[f2][ks] = *(const bf16x8*)(Abuf + ah * 8192 + (row * 8 + ch) * 8);
          }
        }
      }
      if (r != 2) {  // fresh B-half (r2 reuses r1's bh=1)
#pragma unroll
        for (int g2 = 0; g2 < 2; ++g2) {
          const int row = (g2 * 4 + wni) * 16 + ln;
#pragma unroll
          for (int ks = 0; ks < 2; ++ks) {
            const int ch = (ks * 4 + quad) ^ lnx;
            bfr[g2][ks] = *(const bf16x8*)(Bbuf + bh * 8192 + (row * 8 + ch) * 8);
          }
        }
      }
      __builtin_amdgcn_s_setprio(1);
#pragma unroll
      for (int f2 = 0; f2 < 4; ++f2)
#pragma unroll
        for (int g2 = 0; g2 < 2; ++g2)
#pragma unroll
          for (int ks = 0; ks < 2; ++ks)
            acc[ah * 4 + f2][bh * 2 + g2] =
                __builtin_amdgcn_mfma_f32_16x16x32_bf16(
                    af[f2][ks], bfr[g2][ks], acc[ah * 4 + f2][bh * 2 + g2],
                    0, 0, 0);
      __builtin_amdgcn_s_setprio(0);
      asm volatile("s_barrier" ::: "memory");
    }
  }

  // ---- R13 epilogue: LDS-staged coalesced C store (+resid in read phase) --
  // chunk = 128 rows x 256 cols u16; row stride 264 u16 (528B: 16B-aligned,
  // bank-skew 4/row). K-loop's closing barrier guarantees staging LDS free.
  u16* cl = (u16*)lds;
  constexpr int LST = 264;
#pragma unroll
  for (int half = 0; half < 2; ++half) {
    __syncthreads();
#pragma unroll
    for (int f2 = 0; f2 < 4; ++f2) {
      const int f = half * 4 + f2;
#pragma unroll
      for (int g = 0; g < 4; ++g) {
        const int nl = (g * 4 + wni) * 16 + ln;
        const float bv = b2f(bias[n0 + nl]);
#pragma unroll
        for (int rr = 0; rr < 4; ++rr) {
          float v = acc[f][g][rr] + bv;
          if (MODE == 0) v = 0.5f * v * (1.0f + erff(v * 0.70710678118654752f));
          cl[((f2 * 2 + wmi) * 16 + quad * 4 + rr) * LST + nl] = f2b(v);
        }
      }
    }
    __syncthreads();
    // 512 threads read 128x256 u16 (4096 16B slots, 8 per thread), store
    // contiguous uint4: per wave 2 rows x 512B segments.
#pragma unroll
    for (int i = 0; i < 8; ++i) {
      const int s = i * 512 + tid;
      const int rrow = s >> 5, c8 = (s & 31) * 8;
      uint4 v = *(const uint4*)(cl + rrow * LST + c8);
      const size_t gm = (size_t)(m0 + half * 128 + rrow) * N + n0 + c8;
      if (MODE == 1) {
        const uint4 rv = *(const uint4*)(resid + gm);
        unsigned* vp = (unsigned*)&v;
        const unsigned* rp = (const unsigned*)&rv;
#pragma unroll
        for (int q = 0; q < 4; ++q) {
          const float a0 =
              b2f((u16)(vp[q] & 0xFFFF)) + b2f((u16)(rp[q] & 0xFFFF));
          const float a1 = b2f((u16)(vp[q] >> 16)) + b2f((u16)(rp[q] >> 16));
          vp[q] = (unsigned)f2b(a0) | ((unsigned)f2b(a1) << 16);
        }
      }
      *(uint4*)(C + gm) = v;
    }
  }
}

// --------------------------------------------------------------------------
// 3x3 windowed local attention (zero-padded borders), sliding-window form.
// XCD-chunked blocks: physical p serves logical lb = (p&7)*128 + (p>>3);
// one logical block = one full image row (8 runs of 8 px) -> adjacent rows
// (sharing 2/3 of K/V halo) live on one XCD's L2.
// Each 32-lane half-wave owns an 8-px x-run; lane = 8 channels. K/V halo in
// packed uint4 regs with 1-px-ahead prefetch. OOB zero-filled (== reference
// zero-padded semantics). out = hnew + attn.
// --------------------------------------------------------------------------
__global__ __launch_bounds__(256) void attn_kernel(void* __restrict__ outv) {
  const int wv = threadIdx.x >> 6, lane = threadIdx.x & 63;
  const int half = lane >> 5, cl = lane & 31;
  const int c0 = cl * 8;
  const int lb = (blockIdx.x & 7) * 128 + (blockIdx.x >> 3);  // XCD chunk
  const int run = lb * 8 + wv * 2 + half;  // 8192 runs of 8 px
  const int row = run >> 3;                // absolute row b*64+y
  const int y = row & 63;
  const int x0 = (run & 7) * 8;
  const int fp32 = g_flag;

  uint4 Kw[3][3], Vw[3][3], tK[3], tV[3];
  auto fetch = [&](int xx, uint4 (&K3)[3], uint4 (&V3)[3]) {
#pragma unroll
    for (int r = 0; r < 3; ++r) {
      const int yy = y - 1 + r;
      if (((unsigned)yy < 64u) && ((unsigned)xx < 64u)) {
        const size_t np = (size_t)(row - 1 + r) * 64 + xx;
        K3[r] = *(const uint4*)(g_perc + np * 768 + 256 + c0);
        V3[r] = *(const uint4*)(g_perc + np * 768 + 512 + c0);
      } else {
        K3[r] = make_uint4(0, 0, 0, 0);
        V3[r] = make_uint4(0, 0, 0, 0);
      }
    }
  };
  // prologue: cols x0-1 -> slot0, x0 -> slot1, x0+1 -> tmp
  fetch(x0 - 1, tK, tV);
#pragma unroll
  for (int r = 0; r < 3; ++r) { Kw[r][0] = tK[r]; Vw[r][0] = tV[r]; }
  fetch(x0, tK, tV);
#pragma unroll
  for (int r = 0; r < 3; ++r) { Kw[r][1] = tK[r]; Vw[r][1] = tV[r]; }
  fetch(x0 + 1, tK, tV);

#pragma unroll
  for (int k = 0; k < 8; ++k) {
    const int x = x0 + k;
    const int sR = (k + 2) % 3;  // slot receiving col x+1 (from tmp)
#pragma unroll
    for (int r = 0; r < 3; ++r) { Kw[r][sR] = tK[r]; Vw[r][sR] = tV[r]; }
    fetch(x + 2, tK, tV);  // prefetch next px's right col (OOB-safe)

    const size_t pix = (size_t)row * 64 + x;
    float q[8];
    ld8(g_perc + pix * 768 + c0, q);
    float a[8];
    ld8(g_hnew + pix * 256 + c0, a);

    float s[9];
#pragma unroll
    for (int j = 0; j < 9; ++j) {
      float kv[8];
      up8(Kw[j / 3][(k + j % 3) % 3], kv);  // col x-1+(j%3)
      float p = q[0] * kv[0] + q[1] * kv[1] + q[2] * kv[2] + q[3] * kv[3] +
                q[4] * kv[4] + q[5] * kv[5] + q[6] * kv[6] + q[7] * kv[7];
#pragma unroll
      for (int off = 16; off >= 1; off >>= 1) p += __shfl_xor(p, off, 64);
      s[j] = p * 0.0625f;  // 1/sqrt(256)
    }
    float mx = s[0];
#pragma unroll
    for (int j = 1; j < 9; ++j) mx = fmaxf(mx, s[j]);
    float e[9], den = 0.0f;
#pragma unroll
    for (int j = 0; j < 9; ++j) {
      e[j] = expf(s[j] - mx);
      den += e[j];
    }
    const float inv = 1.0f / den;
#pragma unroll
    for (int j = 0; j < 9; ++j) {
      const float wgt = e[j] * inv;
      float vv[8];
      up8(Vw[j / 3][(k + j % 3) % 3], vv);
#pragma unroll
      for (int t = 0; t < 8; ++t) a[t] += wgt * vv[t];
    }
    const size_t o = pix * 256 + c0;
    if (fp32) {
      float4 r0 = {a[0], a[1], a[2], a[3]};
      float4 r1 = {a[4], a[5], a[6], a[7]};
      *(float4*)((float*)outv + o) = r0;
      *(float4*)((float*)outv + o + 4) = r1;
    } else {
      uint4 r;
      r.x = (unsigned)f2b(a[0]) | ((unsigned)f2b(a[1]) << 16);
      r.y = (unsigned)f2b(a[2]) | ((unsigned)f2b(a[3]) << 16);
      r.z = (unsigned)f2b(a[4]) | ((unsigned)f2b(a[5]) << 16);
      r.w = (unsigned)f2b(a[6]) | ((unsigned)f2b(a[7]) << 16);
      *(uint4*)((u16*)outv + o) = r;
    }
  }
}

// --------------------------------------------------------------------------
extern "C" void kernel_launch(void* const* d_in, const int* in_sizes, int n_in,
                              void* d_out, int d_out_size, void* d_ws,
                              size_t ws_size, hipStream_t stream) {
  (void)d_ws; (void)ws_size;
  probe_kernel<<<1, 256, 0, stream>>>((const u16*)d_in[0]);
  conv_w_kernel<<<360, 256, 0, stream>>>(d_in[1], d_in[2], d_in[3], d_in[4],
                                         d_in[5], d_in[6], d_in[7], d_in[8]);
  // perception + h canonicalization (2048 blocks, XCD-chunked)
  perc_kernel<<<2048, 256, 0, stream>>>(d_in[0]);
  // hid = GELU(perceived @ w_up1^T + b_up1)   [65536 x 512, K=768]
  gemm_bt<0, 2><<<512, 512, 0, stream>>>(768);
  // h_new = h + hid @ w_up2^T + b_up2         [65536 x 256, K=512]
  gemm_bt<1, 1><<<256, 512, 0, stream>>>(512);
  // qkv = h_new @ w_qkv^T + b_qkv             [65536 x 768, K=256]
  gemm_bt<2, 3><<<768, 512, 0, stream>>>(256);
  // out = h_new + local_attn(qkv)  (1024 blocks, XCD-chunked; 1 row each)
  attn_kernel<<<1024, 256, 0, stream>>>(d_out);
}

// Round 7
// 381.576 us; speedup vs baseline: 1.5782x; 1.5302x over previous
//
#include <hip/hip_runtime.h>
#include <math.h>

// B=16, H=64, W=64, C=256; M=65536 pixels. Inputs fp32 (runtime-detected),
// canonicalized to bf16. Compute: bf16 MFMA 16x16x32, fp32 accum.
// R14: the three GEMMs fused into ONE kernel (chain is row-local): per
// 128-row block: phase A perceived@W1+GELU -> hid kept in LDS (128KB, XOR
// layout); phase B hid@W2 + h -> hnew (global for attn + LDS 64KB); phase C
// hnew@Wqkv -> qkv chunks. Deletes hid write+read (134MB) and hnew re-read
// (33MB) from HBM; A read once (was twice). Rationale: R8-R13 eliminated
// schedule (3 structures tie), epilogue coalescing (neutral), bank conflicts
// (0) -- GEMM trio is stream-delivery-bound; only deleting bytes moves it
// (proved by R9 attn -50us). LDS 160KB exactly, 1 block/CU, 512 blocks.
// Numerics: identical rounding path to the R12-proven config.
// perc/attn/probe/conv_w unchanged from R13 (XCD-chunked swizzles kept).

typedef unsigned short u16;
typedef __bf16 bf16x8 __attribute__((ext_vector_type(8)));
typedef float floatx4 __attribute__((ext_vector_type(4)));

__device__ int g_flag;  // 0 = bf16 inputs, 1 = fp32 inputs
__device__ __align__(16) u16 g_h[16777216];     // canonical bf16 h  [65536,256]
__device__ __align__(16) u16 g_perc[50331648];  // perceived/qkv     [65536,768]
__device__ __align__(16) u16 g_hnew[16777216];  // h_new             [65536,256]
__device__ __align__(16) u16 g_wperc[6912];
__device__ __align__(16) u16 g_bperc[768];
__device__ __align__(16) u16 g_wup1[393216];
__device__ __align__(16) u16 g_bup1[512];
__device__ __align__(16) u16 g_wup2[131072];
__device__ __align__(16) u16 g_bup2[256];
__device__ __align__(16) u16 g_wqkv[196608];
__device__ __align__(16) u16 g_bqkv[768];

__device__ __forceinline__ float b2f(u16 x) {
  unsigned int u = ((unsigned int)x) << 16;
  float f;
  __builtin_memcpy(&f, &u, 4);
  return f;
}
__device__ __forceinline__ u16 f2b(float f) {
  unsigned int u;
  __builtin_memcpy(&u, &f, 4);
  u += 0x7FFFu + ((u >> 16) & 1u);  // round-to-nearest-even
  return (u16)(u >> 16);
}
// async global->LDS, 16B per lane; LDS dest = wave-uniform base + lane*16.
__device__ __forceinline__ void gload16(const u16* g, u16* l) {
  __builtin_amdgcn_global_load_lds(
      (const __attribute__((address_space(1))) unsigned int*)g,
      (__attribute__((address_space(3))) unsigned int*)l, 16, 0, 0);
}
__device__ __forceinline__ void up8(const uint4& v, float* f) {
  f[0] = b2f((u16)(v.x & 0xFFFF)); f[1] = b2f((u16)(v.x >> 16));
  f[2] = b2f((u16)(v.y & 0xFFFF)); f[3] = b2f((u16)(v.y >> 16));
  f[4] = b2f((u16)(v.z & 0xFFFF)); f[5] = b2f((u16)(v.z >> 16));
  f[6] = b2f((u16)(v.w & 0xFFFF)); f[7] = b2f((u16)(v.w >> 16));
}
__device__ __forceinline__ void ld8(const u16* p, float* f) {
  uint4 v = *(const uint4*)p;
  up8(v, f);
}

// --------------------------------------------------------------------------
// dtype probe: even u16 halves of fp32 data hit exp==0xFF w.p. 1/256;
// bf16 N(0,1) data never does.
// --------------------------------------------------------------------------
__global__ __launch_bounds__(256) void probe_kernel(const u16* __restrict__ h) {
  __shared__ int hit;
  if (threadIdx.x == 0) hit = 0;
  __syncthreads();
  int local = 0;
  for (int i = threadIdx.x; i < 8192; i += 256) {
    u16 v = h[2 * i];
    if ((v & 0x7F80) == 0x7F80) local = 1;
  }
  if (local) atomicOr(&hit, 1);
  __syncthreads();
  if (threadIdx.x == 0) g_flag = hit;
}

// canonicalize all 8 weight/bias tensors in one launch
__global__ __launch_bounds__(256) void conv_w_kernel(
    const void* i1, const void* i2, const void* i3, const void* i4,
    const void* i5, const void* i6, const void* i7, const void* i8) {
  const void* srcs[8] = {i1, i2, i3, i4, i5, i6, i7, i8};
  u16* dsts[8] = {g_wperc, g_bperc, g_wup1, g_bup1,
                  g_wup2,  g_bup2,  g_wqkv, g_bqkv};
  const int szs[8] = {6912, 768, 393216, 512, 131072, 256, 196608, 768};
  const int fp32 = g_flag;
  const int stride = gridDim.x * 256;
  for (int gw = blockIdx.x * 256 + threadIdx.x; gw < 730112; gw += stride) {
    int seg = 0, off = gw;
    while (off >= szs[seg]) { off -= szs[seg]; ++seg; }
    dsts[seg][off] = fp32 ? f2b(((const float*)srcs[seg])[off])
                          : ((const u16*)srcs[seg])[off];
  }
}

// --------------------------------------------------------------------------
// grouped 3x3 perception conv fused with h->bf16 canonicalization.
// 2048 blocks, XCD-chunked. Wave = 16-px x-strip, lane = 2-channel group.
// Reads raw h (fp32/bf16 per g_flag); writes g_h (bf16) + g_perc [pix][768].
// --------------------------------------------------------------------------
__global__ __launch_bounds__(256) void perc_kernel(const void* __restrict__ hin) {
  __shared__ __align__(16) u16 sw[3456];
  __shared__ __align__(16) u16 sb[384];
  const int lb = (blockIdx.x & 7) * 256 + (blockIdx.x >> 3);  // XCD chunk
  const int bid = lb >> 1;  // b*64 + y
  const int chalf = lb & 1;
  const int b = bid >> 6, y = bid & 63;
  const int xi = threadIdx.x >> 6;  // wave id: x-strip
  const int cl = threadIdx.x & 63;  // 2-channel group within half
  const int c0 = chalf * 128 + cl * 2;
  for (int i = threadIdx.x; i < 3456; i += 256) sw[i] = g_wperc[chalf * 3456 + i];
  for (int i = threadIdx.x; i < 384; i += 256) sb[i] = g_bperc[chalf * 384 + i];
  const int fp32 = g_flag;
  __syncthreads();
  float w[2][27], bias[2][3];
#pragma unroll
  for (int ch = 0; ch < 2; ++ch) {
    const int lc = cl * 2 + ch;  // local channel within half
#pragma unroll
    for (int t = 0; t < 3; ++t) {
      bias[ch][t] = b2f(sb[3 * lc + t]);
#pragma unroll
      for (int j = 0; j < 9; ++j)
        w[ch][t * 9 + j] = b2f(sw[(3 * lc + t) * 9 + j]);
    }
  }
  float hv[3][3][2];  // [row][colslot][ch]
  auto loadcol = [&](int xx, int cc) {
#pragma unroll
    for (int r = 0; r < 3; ++r) {
      const int yy = y - 1 + r;
      const bool ok = ((unsigned)yy < 64u) && ((unsigned)xx < 64u);
      if (ok) {
        const size_t idx = (((size_t)(b * 64 + yy) * 64) + xx) * 256 + c0;
        if (fp32) {
          const float2 v = *(const float2*)((const float*)hin + idx);
          hv[r][cc][0] = v.x;
          hv[r][cc][1] = v.y;
        } else {
          const unsigned v = *(const unsigned*)((const u16*)hin + idx);
          hv[r][cc][0] = b2f((u16)(v & 0xFFFF));
          hv[r][cc][1] = b2f((u16)(v >> 16));
        }
      } else {
        hv[r][cc][0] = 0.0f;
        hv[r][cc][1] = 0.0f;
      }
    }
  };
  const int x0 = xi * 16;
  loadcol(x0 - 1, 0);
  loadcol(x0, 1);
#pragma unroll
  for (int k = 0; k < 16; ++k) {
    const int x = x0 + k;
    loadcol(x + 1, (k + 2) % 3);
    const int cL = k % 3, cM = (k + 1) % 3, cR = (k + 2) % 3;
    const size_t pix = (size_t)(b * 64 + y) * 64 + x;
    *(unsigned*)&g_h[pix * 256 + c0] =
        (unsigned)f2b(hv[1][cM][0]) | ((unsigned)f2b(hv[1][cM][1]) << 16);
    u16* op = &g_perc[pix * 768 + 3 * c0];  // lane stride 6 u16 = 12 B
    unsigned pk[3];
#pragma unroll
    for (int ch = 0; ch < 2; ++ch) {
#pragma unroll
      for (int t = 0; t < 3; ++t) {
        const float* wt = &w[ch][t * 9];
        float a = bias[ch][t];
        a += hv[0][cL][ch] * wt[0] + hv[0][cM][ch] * wt[1] + hv[0][cR][ch] * wt[2];
        a += hv[1][cL][ch] * wt[3] + hv[1][cM][ch] * wt[4] + hv[1][cR][ch] * wt[5];
        a += hv[2][cL][ch] * wt[6] + hv[2][cM][ch] * wt[7] + hv[2][cR][ch] * wt[8];
        const int o = 3 * ch + t;
        const unsigned bb = f2b(a);
        if (o & 1) pk[o >> 1] |= bb << 16; else pk[o >> 1] = bb;
      }
    }
    *(unsigned*)(op) = pk[0];
    *(unsigned*)(op + 2) = pk[1];
    *(unsigned*)(op + 4) = pk[2];
  }
}

// --------------------------------------------------------------------------
// Fused MLP+QKV: per 128-row block, phases A/B/C (see header). 512 threads
// = 8 waves, 2M x 4N. LDS map (u16 idx):
//   phase A: Asta[2] @0/8192 (16KB ea), Bsta[2] @16384/49152 (64KB ea)
//   hid 128x512 @0..65535 (XOR(row&7) on low-3 chunk bits)
//   phase B: W2 tiles (256x32=16KB) dbuf @65536/73728
//   hnewL 128x256 @0..32767;  phase C: Wqkv tiles (256x64=32KB) x3 @32768+
// Sync: phase A/B vmcnt(0)->barrier->issue-next->reads (dbuf, 1-ahead);
// phase C 3-buffer 2-ahead with counted vmcnt(4).
// --------------------------------------------------------------------------
__global__ __launch_bounds__(512, 2) void fused_mlp_qkv() {
  __shared__ __align__(16) u16 L[81920];  // 160 KB
  const int tid = threadIdx.x;
  const int w = tid >> 6, lane = tid & 63;
  const int ln = lane & 15, quad = lane >> 4, lnx = ln & 7;
  const int wmi = w >> 2, wni = w & 3;  // 2M x 4N
  const int m_blk = (blockIdx.x & 7) * 64 + (blockIdx.x >> 3);  // XCD swizzle
  const int m0 = m_blk * 128;

  auto stageA = [&](int t) {  // perceived 128x64 -> @ (t&1)*8192
    u16* dst = &L[(t & 1) * 8192];
#pragma unroll
    for (int ld = 0; ld < 2; ++ld) {
      const int s = ld * 512 + tid;
      const int sr = s >> 3, sc = (s & 7) ^ (sr & 7);
      gload16(&g_perc[(size_t)(m0 + sr) * 768 + t * 64 + sc * 8], dst + s * 8);
    }
  };
  auto stageB1 = [&](int t) {  // W1 512x64 -> @16384 + (t&1)*32768
    u16* dst = &L[16384 + (t & 1) * 32768];
#pragma unroll
    for (int ld = 0; ld < 8; ++ld) {
      const int s = ld * 512 + tid;
      const int sr = s >> 3, sc = (s & 7) ^ (sr & 7);
      gload16(&g_wup1[(size_t)sr * 768 + t * 64 + sc * 8], dst + s * 8);
    }
  };

  // ---------------- phase A: hid = GELU(perceived @ W1^T + b1) -------------
  floatx4 acc[4][8] = {};
  stageA(0); stageB1(0);
  for (int u = 0; u < 12; ++u) {
    asm volatile("s_waitcnt vmcnt(0)" ::: "memory");
    __builtin_amdgcn_s_barrier();
    if (u + 1 < 12) { stageA(u + 1); stageB1(u + 1); }
    const u16* Ab = &L[(u & 1) * 8192];
    const u16* Bb = &L[16384 + (u & 1) * 32768];
    bf16x8 a[4][2];
#pragma unroll
    for (int i = 0; i < 4; ++i) {
      const int row = wmi * 64 + i * 16 + ln;
#pragma unroll
      for (int ks = 0; ks < 2; ++ks)
        a[i][ks] = *(const bf16x8*)(Ab + (row * 8 + ((ks * 4 + quad) ^ lnx)) * 8);
    }
    __builtin_amdgcn_s_setprio(1);
#pragma unroll
    for (int jg = 0; jg < 2; ++jg) {  // B-frags in 2 groups (VGPR pressure)
      bf16x8 b[4][2];
#pragma unroll
      for (int jj = 0; jj < 4; ++jj) {
        const int row = wni * 128 + (jg * 4 + jj) * 16 + ln;
#pragma unroll
        for (int ks = 0; ks < 2; ++ks)
          b[jj][ks] =
              *(const bf16x8*)(Bb + (row * 8 + ((ks * 4 + quad) ^ lnx)) * 8);
      }
#pragma unroll
      for (int i = 0; i < 4; ++i)
#pragma unroll
        for (int jj = 0; jj < 4; ++jj)
#pragma unroll
          for (int ks = 0; ks < 2; ++ks)
            acc[i][jg * 4 + jj] = __builtin_amdgcn_mfma_f32_16x16x32_bf16(
                a[i][ks], b[jj][ks], acc[i][jg * 4 + jj], 0, 0, 0);
    }
    __builtin_amdgcn_s_setprio(0);
  }
  __builtin_amdgcn_s_barrier();  // all staging reads done; LDS free for hid
  // GELU -> bf16 -> hid LDS: addr (row*64 + (ch&56 | (ch&7 ^ row&7)))*8+(n&7)
#pragma unroll
  for (int i = 0; i < 4; ++i) {
#pragma unroll
    for (int j = 0; j < 8; ++j) {
      const int n = wni * 128 + j * 16 + ln;
      const float bv = b2f(g_bup1[n]);
      const int ch = n >> 3;
#pragma unroll
      for (int rr = 0; rr < 4; ++rr) {
        const int r = wmi * 64 + i * 16 + quad * 4 + rr;
        float v = acc[i][j][rr] + bv;
        v = 0.5f * v * (1.0f + erff(v * 0.70710678118654752f));
        L[((size_t)r * 64 + ((ch & 56) | ((ch & 7) ^ (r & 7)))) * 8 + (n & 7)] =
            f2b(v);
      }
    }
  }
  asm volatile("s_waitcnt lgkmcnt(0)" ::: "memory");
  __builtin_amdgcn_s_barrier();

  // ---------------- phase B: hnew = hid @ W2^T + b2 + h --------------------
  auto stageW2 = [&](int t) {  // W2 256x32 -> @65536 + (t&1)*8192
    u16* dst = &L[65536 + (t & 1) * 8192];
#pragma unroll
    for (int ld = 0; ld < 2; ++ld) {
      const int s = ld * 512 + tid;
      const int sr = s >> 2, sc = (s & 3) ^ (sr & 3);
      gload16(&g_wup2[(size_t)sr * 512 + t * 32 + sc * 8], dst + s * 8);
    }
  };
  floatx4 acB[4][4] = {};
  stageW2(0);
  for (int t = 0; t < 16; ++t) {
    asm volatile("s_waitcnt vmcnt(0)" ::: "memory");
    __builtin_amdgcn_s_barrier();
    if (t + 1 < 16) stageW2(t + 1);
    const u16* Wb = &L[65536 + (t & 1) * 8192];
    const int kt = t >> 1, ks = t & 1;
    bf16x8 a[4], b[4];
#pragma unroll
    for (int i = 0; i < 4; ++i) {
      const int row = wmi * 64 + i * 16 + ln;
      a[i] = *(const bf16x8*)(
          &L[((size_t)row * 64 + kt * 8 + ((ks * 4 + quad) ^ (row & 7))) * 8]);
    }
#pragma unroll
    for (int j = 0; j < 4; ++j) {
      const int row = wni * 64 + j * 16 + ln;
      b[j] = *(const bf16x8*)(Wb + (row * 4 + (quad ^ (row & 3))) * 8);
    }
    __builtin_amdgcn_s_setprio(1);
#pragma unroll
    for (int i = 0; i < 4; ++i)
#pragma unroll
      for (int j = 0; j < 4; ++j)
        acB[i][j] = __builtin_amdgcn_mfma_f32_16x16x32_bf16(a[i], b[j],
                                                            acB[i][j], 0, 0, 0);
    __builtin_amdgcn_s_setprio(0);
  }
  __builtin_amdgcn_s_barrier();  // hid reads done; hid area reusable
  // epilogue B: + bias + resid; -> g_hnew (global) and hnewL (LDS @0)
#pragma unroll
  for (int i = 0; i < 4; ++i) {
#pragma unroll
    for (int j = 0; j < 4; ++j) {
      const int n = wni * 64 + j * 16 + ln;
      const float bv = b2f(g_bup2[n]);
      const int ch = n >> 3;  // 0..31
#pragma unroll
      for (int rr = 0; rr < 4; ++rr) {
        const int r = wmi * 64 + i * 16 + quad * 4 + rr;
        float v = acB[i][j][rr] + bv;
        v += b2f(g_h[(size_t)(m0 + r) * 256 + n]);
        const u16 bb = f2b(v);
        g_hnew[(size_t)(m0 + r) * 256 + n] = bb;
        L[((size_t)r * 32 + ((ch & 24) | ((ch & 7) ^ (r & 7)))) * 8 + (n & 7)] =
            bb;
      }
    }
  }
  // ---------------- phase C: qkv = hnew @ Wqkv^T + bqkv --------------------
  auto stageWq = [&](int tt) {  // chunk tt>>2, ktile tt&3: 256x64 -> 3-buf
    u16* dst = &L[32768 + (tt % 3) * 16384];
    const int c = tt >> 2, t = tt & 3;
#pragma unroll
    for (int ld = 0; ld < 4; ++ld) {
      const int s = ld * 512 + tid;
      const int sr = s >> 3, sc = (s & 7) ^ (sr & 7);
      gload16(&g_wqkv[(size_t)(c * 256 + sr) * 256 + t * 64 + sc * 8],
              dst + s * 8);
    }
  };
  stageWq(0);
  stageWq(1);
  asm volatile("s_waitcnt lgkmcnt(0)" ::: "memory");
  __builtin_amdgcn_s_barrier();
  for (int c = 0; c < 3; ++c) {
    floatx4 acC[4][4] = {};
    for (int t = 0; t < 4; ++t) {
      const int tt = c * 4 + t;
      if (tt < 11) asm volatile("s_waitcnt vmcnt(4)" ::: "memory");
      else         asm volatile("s_waitcnt vmcnt(0)" ::: "memory");
      __builtin_amdgcn_s_barrier();
      if (tt + 2 < 12) stageWq(tt + 2);
      const u16* Wb = &L[32768 + (tt % 3) * 16384];
      bf16x8 a[4][2], b[4][2];
#pragma unroll
      for (int i = 0; i < 4; ++i) {
        const int row = wmi * 64 + i * 16 + ln;
#pragma unroll
        for (int ks = 0; ks < 2; ++ks)
          a[i][ks] = *(const bf16x8*)(
              &L[((size_t)row * 32 + t * 8 + ((ks * 4 + quad) ^ (row & 7))) *
                 8]);
      }
#pragma unroll
      for (int j = 0; j < 4; ++j) {
        const int row = wni * 64 + j * 16 + ln;
#pragma unroll
        for (int ks = 0; ks < 2; ++ks)
          b[j][ks] =
              *(const bf16x8*)(Wb + (row * 8 + ((ks * 4 + quad) ^ lnx)) * 8);
      }
      __builtin_amdgcn_s_setprio(1);
#pragma unroll
      for (int i = 0; i < 4; ++i)
#pragma unroll
        for (int j = 0; j < 4; ++j)
#pragma unroll
          for (int ks = 0; ks < 2; ++ks)
            acC[i][j] = __builtin_amdgcn_mfma_f32_16x16x32_bf16(
                a[i][ks], b[j][ks], acC[i][j], 0, 0, 0);
      __builtin_amdgcn_s_setprio(0);
    }
#pragma unroll
    for (int i = 0; i < 4; ++i) {
#pragma unroll
      for (int j = 0; j < 4; ++j) {
        const int n = wni * 64 + j * 16 + ln;
        const float bv = b2f(g_bqkv[c * 256 + n]);
#pragma unroll
        for (int rr = 0; rr < 4; ++rr) {
          const int r = wmi * 64 + i * 16 + quad * 4 + rr;
          g_perc[(size_t)(m0 + r) * 768 + c * 256 + n] = f2b(acC[i][j][rr] + bv);
        }
      }
    }
  }
}

// --------------------------------------------------------------------------
// 3x3 windowed local attention (zero-padded borders), sliding-window form.
// XCD-chunked blocks; 32-lane half-wave owns an 8-px x-run; lane = 8 ch.
// K/V halo in packed uint4 regs, 1-px-ahead prefetch. out = hnew + attn.
// --------------------------------------------------------------------------
__global__ __launch_bounds__(256) void attn_kernel(void* __restrict__ outv) {
  const int wv = threadIdx.x >> 6, lane = threadIdx.x & 63;
  const int half = lane >> 5, cl = lane & 31;
  const int c0 = cl * 8;
  const int lb = (blockIdx.x & 7) * 128 + (blockIdx.x >> 3);  // XCD chunk
  const int run = lb * 8 + wv * 2 + half;
  const int row = run >> 3;
  const int y = row & 63;
  const int x0 = (run & 7) * 8;
  const int fp32 = g_flag;

  uint4 Kw[3][3], Vw[3][3], tK[3], tV[3];
  auto fetch = [&](int xx, uint4 (&K3)[3], uint4 (&V3)[3]) {
#pragma unroll
    for (int r = 0; r < 3; ++r) {
      const int yy = y - 1 + r;
      if (((unsigned)yy < 64u) && ((unsigned)xx < 64u)) {
        const size_t np = (size_t)(row - 1 + r) * 64 + xx;
        K3[r] = *(const uint4*)(g_perc + np * 768 + 256 + c0);
        V3[r] = *(const uint4*)(g_perc + np * 768 + 512 + c0);
      } else {
        K3[r] = make_uint4(0, 0, 0, 0);
        V3[r] = make_uint4(0, 0, 0, 0);
      }
    }
  };
  fetch(x0 - 1, tK, tV);
#pragma unroll
  for (int r = 0; r < 3; ++r) { Kw[r][0] = tK[r]; Vw[r][0] = tV[r]; }
  fetch(x0, tK, tV);
#pragma unroll
  for (int r = 0; r < 3; ++r) { Kw[r][1] = tK[r]; Vw[r][1] = tV[r]; }
  fetch(x0 + 1, tK, tV);

#pragma unroll
  for (int k = 0; k < 8; ++k) {
    const int x = x0 + k;
    const int sR = (k + 2) % 3;
#pragma unroll
    for (int r = 0; r < 3; ++r) { Kw[r][sR] = tK[r]; Vw[r][sR] = tV[r]; }
    fetch(x + 2, tK, tV);

    const size_t pix = (size_t)row * 64 + x;
    float q[8];
    ld8(g_perc + pix * 768 + c0, q);
    float a[8];
    ld8(g_hnew + pix * 256 + c0, a);

    float s[9];
#pragma unroll
    for (int j = 0; j < 9; ++j) {
      float kv[8];
      up8(Kw[j / 3][(k + j % 3) % 3], kv);
      float p = q[0] * kv[0] + q[1] * kv[1] + q[2] * kv[2] + q[3] * kv[3] +
                q[4] * kv[4] + q[5] * kv[5] + q[6] * kv[6] + q[7] * kv[7];
#pragma unroll
      for (int off = 16; off >= 1; off >>= 1) p += __shfl_xor(p, off, 64);
      s[j] = p * 0.0625f;
    }
    float mx = s[0];
#pragma unroll
    for (int j = 1; j < 9; ++j) mx = fmaxf(mx, s[j]);
    float e[9], den = 0.0f;
#pragma unroll
    for (int j = 0; j < 9; ++j) {
      e[j] = expf(s[j] - mx);
      den += e[j];
    }
    const float inv = 1.0f / den;
#pragma unroll
    for (int j = 0; j < 9; ++j) {
      const float wgt = e[j] * inv;
      float vv[8];
      up8(Vw[j / 3][(k + j % 3) % 3], vv);
#pragma unroll
      for (int t = 0; t < 8; ++t) a[t] += wgt * vv[t];
    }
    const size_t o = pix * 256 + c0;
    if (fp32) {
      float4 r0 = {a[0], a[1], a[2], a[3]};
      float4 r1 = {a[4], a[5], a[6], a[7]};
      *(float4*)((float*)outv + o) = r0;
      *(float4*)((float*)outv + o + 4) = r1;
    } else {
      uint4 r;
      r.x = (unsigned)f2b(a[0]) | ((unsigned)f2b(a[1]) << 16);
      r.y = (unsigned)f2b(a[2]) | ((unsigned)f2b(a[3]) << 16);
      r.z = (unsigned)f2b(a[4]) | ((unsigned)f2b(a[5]) << 16);
      r.w = (unsigned)f2b(a[6]) | ((unsigned)f2b(a[7]) << 16);
      *(uint4*)((u16*)outv + o) = r;
    }
  }
}

// --------------------------------------------------------------------------
extern "C" void kernel_launch(void* const* d_in, const int* in_sizes, int n_in,
                              void* d_out, int d_out_size, void* d_ws,
                              size_t ws_size, hipStream_t stream) {
  (void)d_ws; (void)ws_size;
  probe_kernel<<<1, 256, 0, stream>>>((const u16*)d_in[0]);
  conv_w_kernel<<<360, 256, 0, stream>>>(d_in[1], d_in[2], d_in[3], d_in[4],
                                         d_in[5], d_in[6], d_in[7], d_in[8]);
  // perception + h canonicalization (2048 blocks, XCD-chunked)
  perc_kernel<<<2048, 256, 0, stream>>>(d_in[0]);
  // fused: perceived -> hid(LDS) -> hnew(global+LDS) -> qkv (g_perc)
  fused_mlp_qkv<<<512, 512, 0, stream>>>();
  // out = h_new + local_attn(qkv)  (1024 blocks, XCD-chunked; 1 row each)
  attn_kernel<<<1024, 256, 0, stream>>>(d_out);
}